// Round 1
// baseline (276.640 us; speedup 1.0000x reference)
//
#include <hip/hip_runtime.h>
#include <math.h>

#define D_DIM 16
#define N_PTS 100
#define VMIN_F (-5.0f)
#define INT_LEN_F (10.0f / 99.0f)
#define INV_INT_LEN_F (99.0f / 10.0f)

// ---------------------------------------------------------------------------
// Setup kernel (1 block, 256 threads):
//  - Gauss-Jordan inverse of (I - A) in fp64 (partial pivoting) -> Minv [16x16]
//  - w_tab[d][j]  = exp(p[d][j]) + 0.001            (16 x 101)
//  - db[d][i]     = b[d] + cumsum(INT_LEN*(exp(p[d][1..i])+0.001))  (16 x 100)
//    (serial per-dim accumulation matches jnp.cumsum fp32 ordering)
// ---------------------------------------------------------------------------
__global__ void scm_setup(const float* __restrict__ A,
                          const float* __restrict__ p,
                          const float* __restrict__ b,
                          float* __restrict__ Minv,
                          float* __restrict__ w_tab,
                          float* __restrict__ db) {
    __shared__ double aug[16][33];   // [I-A | I], padded
    __shared__ int piv;
    const int t = threadIdx.x;

    if (t < 16) {
        #pragma unroll
        for (int j = 0; j < 16; j++) {
            aug[t][j]      = (t == j ? 1.0 : 0.0) - (double)A[t * 16 + j];
            aug[t][16 + j] = (t == j ? 1.0 : 0.0);
        }
    }
    __syncthreads();

    for (int k = 0; k < 16; k++) {
        if (t == 0) {
            int pr = k; double best = fabs(aug[k][k]);
            for (int i = k + 1; i < 16; i++) {
                double v = fabs(aug[i][k]);
                if (v > best) { best = v; pr = i; }
            }
            piv = pr;
        }
        __syncthreads();
        const int pr = piv;
        if (pr != k && t < 32) {
            double tmp = aug[k][t]; aug[k][t] = aug[pr][t]; aug[pr][t] = tmp;
        }
        __syncthreads();
        const double pivval = aug[k][k];
        __syncthreads();
        if (t < 32) aug[k][t] = aug[k][t] / pivval;
        __syncthreads();
        if (t < 16 && t != k) {
            const double f = aug[t][k];
            #pragma unroll
            for (int j = 0; j < 32; j++) aug[t][j] -= f * aug[k][j];
        }
        __syncthreads();
    }

    // Minv[k][d] = inv(I-A)[k][d]  (row-major; z[d] = sum_k eps[k]*Minv[k][d])
    if (t < 16) {
        #pragma unroll
        for (int j = 0; j < 16; j++) Minv[t * 16 + j] = (float)aug[t][16 + j];
    }

    // w table: exp(p) + 0.001 for all 101 knots per dim
    for (int i = t; i < 16 * (N_PTS + 1); i += blockDim.x)
        w_tab[i] = expf(p[i]) + 0.001f;

    // delta_bias: serial cumsum per dim (16 threads), fp32 like reference
    if (t < 16) {
        float acc = b[t];
        db[t * N_PTS + 0] = acc;
        for (int i = 1; i < N_PTS; i++) {
            acc += INT_LEN_F * (expf(p[t * (N_PTS + 1) + i]) + 0.001f);
            db[t * N_PTS + i] = acc;
        }
    }
}

// ---------------------------------------------------------------------------
// Main kernel: one thread per row.
//   z = eps_row @ Minv  (16x16 register matmul, Minv in LDS)
//   out[d] = (z - sp)*w + db  with uniform-grid index arithmetic
// ---------------------------------------------------------------------------
__global__ __launch_bounds__(256) void scm_main(
        const float* __restrict__ eps,
        const float* __restrict__ Minv,
        const float* __restrict__ w_tab,
        const float* __restrict__ db,
        float* __restrict__ out, int B) {
    __shared__ float sM[256];
    __shared__ float sW[16 * (N_PTS + 1)];
    __shared__ float sDB[16 * N_PTS];

    for (int i = threadIdx.x; i < 256; i += 256) sM[i] = Minv[i];
    for (int i = threadIdx.x; i < 16 * (N_PTS + 1); i += 256) sW[i] = w_tab[i];
    for (int i = threadIdx.x; i < 16 * N_PTS; i += 256) sDB[i] = db[i];
    __syncthreads();

    const int row = blockIdx.x * blockDim.x + threadIdx.x;
    if (row >= B) return;

    const float4* erow = (const float4*)(eps + (size_t)row * 16);
    float4 e0 = erow[0], e1 = erow[1], e2 = erow[2], e3 = erow[3];
    float e[16] = {e0.x, e0.y, e0.z, e0.w, e1.x, e1.y, e1.z, e1.w,
                   e2.x, e2.y, e2.z, e2.w, e3.x, e3.y, e3.z, e3.w};

    float z[16];
    #pragma unroll
    for (int d = 0; d < 16; d++) z[d] = 0.0f;

    #pragma unroll
    for (int k = 0; k < 16; k++) {
        const float ek = e[k];
        const float4 m0 = ((const float4*)sM)[k * 4 + 0];
        const float4 m1 = ((const float4*)sM)[k * 4 + 1];
        const float4 m2 = ((const float4*)sM)[k * 4 + 2];
        const float4 m3 = ((const float4*)sM)[k * 4 + 3];
        z[0]  = fmaf(ek, m0.x, z[0]);  z[1]  = fmaf(ek, m0.y, z[1]);
        z[2]  = fmaf(ek, m0.z, z[2]);  z[3]  = fmaf(ek, m0.w, z[3]);
        z[4]  = fmaf(ek, m1.x, z[4]);  z[5]  = fmaf(ek, m1.y, z[5]);
        z[6]  = fmaf(ek, m1.z, z[6]);  z[7]  = fmaf(ek, m1.w, z[7]);
        z[8]  = fmaf(ek, m2.x, z[8]);  z[9]  = fmaf(ek, m2.y, z[9]);
        z[10] = fmaf(ek, m2.z, z[10]); z[11] = fmaf(ek, m2.w, z[11]);
        z[12] = fmaf(ek, m3.x, z[12]); z[13] = fmaf(ek, m3.y, z[13]);
        z[14] = fmaf(ek, m3.z, z[14]); z[15] = fmaf(ek, m3.w, z[15]);
    }

    float o[16];
    #pragma unroll
    for (int d = 0; d < 16; d++) {
        const float zd = z[d];
        // searchsorted(points, z, 'right') on uniform grid:
        // idx = floor((z - vmin)/h) + 1, clamped to [0, 100].
        // PWL is continuous at knots, so boundary rounding is harmless.
        const float tt = (zd - VMIN_F) * INV_INT_LEN_F;
        int idx = (int)floorf(tt) + 1;
        idx = min(max(idx, 0), N_PTS);
        const int sp_idx = max(idx - 1, 0);
        const float sp = VMIN_F + (float)sp_idx * INT_LEN_F;
        const float w  = sW[d * (N_PTS + 1) + idx];
        const float dbv = sDB[d * N_PTS + sp_idx];
        o[d] = fmaf(zd - sp, w, dbv);
    }

    float4* orow = (float4*)(out + (size_t)row * 16);
    orow[0] = make_float4(o[0],  o[1],  o[2],  o[3]);
    orow[1] = make_float4(o[4],  o[5],  o[6],  o[7]);
    orow[2] = make_float4(o[8],  o[9],  o[10], o[11]);
    orow[3] = make_float4(o[12], o[13], o[14], o[15]);
}

extern "C" void kernel_launch(void* const* d_in, const int* in_sizes, int n_in,
                              void* d_out, int out_size, void* d_ws, size_t ws_size,
                              hipStream_t stream) {
    const float* eps = (const float*)d_in[0];
    const float* A   = (const float*)d_in[1];
    const float* p   = (const float*)d_in[2];
    const float* b   = (const float*)d_in[3];
    float* out = (float*)d_out;

    const int B = in_sizes[0] / D_DIM;

    // workspace layout: Minv[256] | w_tab[16*101] | db[16*100]
    float* ws    = (float*)d_ws;
    float* Minv  = ws;
    float* w_tab = ws + 256;
    float* db    = ws + 256 + 16 * (N_PTS + 1);

    scm_setup<<<1, 256, 0, stream>>>(A, p, b, Minv, w_tab, db);

    const int blocks = (B + 255) / 256;
    scm_main<<<blocks, 256, 0, stream>>>(eps, Minv, w_tab, db, out, B);
}